// Round 18
// baseline (343.304 us; speedup 1.0000x reference)
//
#include <hip/hip_runtime.h>

static constexpr int NN = 100000;   // nodes
static constexpr int NE = 1600000;  // edges
static constexpr int C  = 128;      // feature dim
static constexpr int OC = 10;       // output classes
static constexpr int NG = 512;      // graphs

// Bucketed CSR build parameters
static constexpr int BSH  = 9;                         // 512 nodes per bucket
static constexpr int BNW  = 1 << BSH;                  // 512
static constexpr int BK   = (NN + BNW - 1) / BNW;      // 196 buckets
static constexpr int BCAP = 12288;                     // slab capacity (avg ~8163)
static constexpr int EPB  = 4096;                      // edges per binA block
static constexpr int ABLK = (NE + EPB - 1) / EPB;      // 391

static constexpr int TSTRIDE = 132;                    // LDS tile row stride (u16)
static constexpr int NSPLIT = 8;                       // blocks per graph in k_gsum

// merged binA+prep block-range bases (256-thread blocks)
static constexpr int APB_PACK = ABLK;                  // 32 blocks: weight pack
static constexpr int APB_GB   = APB_PACK + 32;         // 3 blocks: gbounds
static constexpr int APB_WF   = APB_GB + 3;            // 10 blocks: wfold
static constexpr int APB_CVT  = APB_WF + 10;           // 6250 blocks: x->bf16
static constexpr int APB_TOT  = APB_CVT + (NN * C / 8 + 255) / 256;

typedef unsigned short u16;
typedef __attribute__((ext_vector_type(8))) short short8;   // 8 bf16 = 16B
typedef __attribute__((ext_vector_type(8))) short bf16x8;   // MFMA A/B frag
typedef __attribute__((ext_vector_type(4))) float f32x4;    // MFMA C/D frag

__device__ __forceinline__ float bf2f(u16 u) {
    union { float f; unsigned int u32; } v; v.u32 = ((unsigned int)u) << 16; return v.f;
}
__device__ __forceinline__ u16 f2bf(float f) {
    union { float f; unsigned int u; } v; v.f = f;
    unsigned int u = v.u;
    unsigned int r = u + 0x7FFF + ((u >> 16) & 1);   // RNE
    return (u16)(r >> 16);
}

// ---------------------------------------------------------------------------
// Merged binA + prep: blocks [0,ABLK) bin edges into buckets; remaining
// blocks do input-only precompute (weight pack, gbounds, wfold, x->bf16).
// ---------------------------------------------------------------------------
__global__ __launch_bounds__(256) void k_binA_prep(
    const int* __restrict__ src, const int* __restrict__ dst,
    int* __restrict__ gcnt, int* __restrict__ buck,
    const float* __restrict__ x, u16* __restrict__ xb,
    const float* __restrict__ W1r, const float* __restrict__ W1o,
    const float* __restrict__ W2r, const float* __restrict__ W2o,
    u16* __restrict__ Bp,
    const int* __restrict__ batch, int* __restrict__ gstart,
    const float* __restrict__ W3r, const float* __restrict__ W3o,
    const float* __restrict__ b3, const float* __restrict__ W_lin,
    const float* __restrict__ b_lin,
    float* __restrict__ Wrl, float* __restrict__ Wro, float* __restrict__ bfold) {
    int bid = blockIdx.x;
    int tid = threadIdx.x;

    if (bid < ABLK) {
        __shared__ int cnt[BK];
        __shared__ int curs[BK];
        for (int i = tid; i < BK; i += 256) cnt[i] = 0;
        __syncthreads();
        int e0 = bid * EPB;
        for (int i = tid; i < EPB; i += 256) {
            int e = e0 + i;
            if (e < NE) atomicAdd(&cnt[dst[e] >> BSH], 1);
        }
        __syncthreads();
        for (int i = tid; i < BK; i += 256) {
            int c = cnt[i];
            int gb = (c > 0) ? atomicAdd(&gcnt[i], c) : 0;
            curs[i] = i * BCAP + gb;
        }
        __syncthreads();
        for (int i = tid; i < EPB; i += 256) {
            int e = e0 + i;
            if (e < NE) {
                int d = dst[e];
                int b = d >> BSH;
                int p = atomicAdd(&curs[b], 1);
                if (p < (b + 1) * BCAP)
                    buck[p] = (src[e] << BSH) | (d & (BNW - 1));
            }
        }
    } else if (bid < APB_GB) {
        int tt = (bid - APB_PACK) * 256 + tid;    // 0..8191
        int layer = tt >> 12;
        int t = tt & 4095;
        const float* Wr = (layer == 0) ? W1r : W2r;
        const float* Wo = (layer == 0) ? W1o : W2o;
        u16* outp = Bp + layer * 32768;
        int lane = t & 63;
        int nfrag = (t >> 6) & 7;
        int kk = t >> 9;
        int col = nfrag * 16 + (lane & 15);
        int k0 = kk * 32 + (lane >> 4) * 8;
        u16 vals[8];
#pragma unroll
        for (int j = 0; j < 8; ++j) {
            int k = k0 + j;
            float w = (k < C) ? Wr[k * C + col] : Wo[(k - C) * C + col];
            vals[j] = f2bf(w);
        }
        *reinterpret_cast<short8*>(outp + (size_t)t * 8) = *reinterpret_cast<const short8*>(vals);
    } else if (bid < APB_WF) {
        int g = (bid - APB_GB) * 256 + tid;
        if (g > NG) return;
        int lo = 0, hi = NN;
        while (lo < hi) { int mid = (lo + hi) >> 1; if (batch[mid] < g) lo = mid + 1; else hi = mid; }
        gstart[g] = lo;
    } else if (bid < APB_CVT) {
        int idx = (bid - APB_WF) * 256 + tid;
        if (idx >= OC * 256) return;
        int o = idx >> 8;
        int sub = idx & 255;
        if (sub < 128) {
            float s = 0.0f;
#pragma unroll 8
            for (int c = 0; c < C; ++c) s += W3r[sub * C + c] * W_lin[c * OC + o];
            Wrl[sub * OC + o] = s;
        } else {
            int k = sub - 128;
            float s = 0.0f;
#pragma unroll 8
            for (int c = 0; c < C; ++c) s += W3o[k * C + c] * W_lin[c * OC + o];
            Wro[k * OC + o] = s;
        }
        if (sub == 0) {
            float s = 0.0f;
            for (int c = 0; c < C; ++c) s += b3[c] * W_lin[c * OC + o];
            bfold[o] = b_lin[o] + s;
        }
    } else {
        int i = (bid - APB_CVT) * 256 + tid;
        size_t base = (size_t)i * 8;
        if (base >= (size_t)NN * C) return;
        float4 a = *reinterpret_cast<const float4*>(x + base);
        float4 b = *reinterpret_cast<const float4*>(x + base + 4);
        u16 o[8] = { f2bf(a.x), f2bf(a.y), f2bf(a.z), f2bf(a.w),
                     f2bf(b.x), f2bf(b.y), f2bf(b.z), f2bf(b.w) };
        *reinterpret_cast<short8*>(xb + base) = *reinterpret_cast<const short8*>(o);
    }
}

// ---------------------------------------------------------------------------
// Phase B: one block per bucket (unchanged).
// ---------------------------------------------------------------------------
__global__ __launch_bounds__(BNW) void k_binB(const int* __restrict__ gcnt,
                                              const int* __restrict__ buck,
                                              int* __restrict__ rp,
                                              int* __restrict__ csr) {
    int b = blockIdx.x;
    int tid = threadIdx.x;
    __shared__ int hist[BNW];
    __shared__ int scanbuf[BNW];

    scanbuf[tid] = (tid < b) ? gcnt[tid] : 0;
    __syncthreads();
    for (int off = 1; off < BNW; off <<= 1) {
        int t = (tid >= off) ? scanbuf[tid - off] : 0;
        __syncthreads();
        scanbuf[tid] += t;
        __syncthreads();
    }
    int base = scanbuf[BNW - 1];

    int n = gcnt[b];
    if (n > BCAP) n = BCAP;
    const int* bb = buck + (size_t)b * BCAP;

    hist[tid] = 0;
    __syncthreads();
    for (int i = tid; i < n; i += BNW) atomicAdd(&hist[bb[i] & (BNW - 1)], 1);
    __syncthreads();

    int v = hist[tid];
    scanbuf[tid] = v;
    __syncthreads();
    for (int off = 1; off < BNW; off <<= 1) {
        int t = (tid >= off) ? scanbuf[tid - off] : 0;
        __syncthreads();
        scanbuf[tid] += t;
        __syncthreads();
    }
    int excl = scanbuf[tid] - v;
    int node = (b << BSH) + tid;
    if (node < NN) rp[node] = base + excl;
    if (b == 0 && tid == 0) rp[NN] = NE;
    __syncthreads();
    hist[tid] = base + excl;
    __syncthreads();
    for (int i = tid; i < n; i += BNW) {
        int en = bb[i];
        int p = atomicAdd(&hist[en & (BNW - 1)], 1);
        csr[p] = en >> BSH;
    }
}

// ---------------------------------------------------------------------------
// Fused layer: gather + MFMA transform.  Block = 4 waves x 16 rows.
// Phase 1: WAVE-PER-NODE gather (round-10 pattern: one neighbor list per
//   wave at a time -> zero divergence; 8 edges/iter in flight), writing the
//   aggregate rows to the LDS tile instead of a global agg buffer.
// Phase 2: A-frags from LDS (agg) + global (root row), B-frags via LDS
//   double-buffer, 64 MFMAs, bias/relu epilogue staged through the same
//   tile for coalesced stores.  hout must differ from hin (ping-pong).
// TSUM: accumulate per-graph column sums of the output tile into Tpart.
// ---------------------------------------------------------------------------
template <bool RELU, bool TSUM>
__global__ __launch_bounds__(256) void k_layer_fused(
    const u16* __restrict__ hin, const int* __restrict__ rp,
    const int* __restrict__ csr, const u16* __restrict__ Bp,
    const float* __restrict__ bias, u16* __restrict__ hout,
    const int* __restrict__ batch, float* __restrict__ Tpart) {
    __shared__ u16 tile[4][16 * TSTRIDE];   // 16.9 KB: agg rows, then out tile
    __shared__ u16 bsl[2][4096];            // 16 KB: B kk-slice double buffer
    int tid = threadIdx.x;
    int wave = tid >> 6;
    int lane = tid & 63;
    int row0 = blockIdx.x * 64 + wave * 16;
    int jj = lane >> 4;          // edge slot 0..3
    int seg = (lane & 15) * 8;   // element offset within row

    // ---- Phase 1: gather this wave's 16 rows into LDS ----
    u16* T = tile[wave];
    for (int r = 0; r < 16; ++r) {
        int node = row0 + r;
        if (node >= NN) break;                    // wave-uniform
        int beg = rp[node], end = rp[node + 1];
        float acc[8] = {};
        int j0 = beg;
        for (; j0 + 8 <= end; j0 += 8) {
            int sa = csr[j0 + jj];
            int sb = csr[j0 + 4 + jj];
            short8 va = *reinterpret_cast<const short8*>(hin + (size_t)sa * C + seg);
            short8 vb = *reinterpret_cast<const short8*>(hin + (size_t)sb * C + seg);
#pragma unroll
            for (int q = 0; q < 8; ++q) {
                acc[q] += bf2f((u16)va[q]);
                acc[q] += bf2f((u16)vb[q]);
            }
        }
        if (j0 < end) {
            int ja = j0 + jj;
            int jb = j0 + 4 + jj;
            if (ja < end) {
                int sa = csr[ja];
                short8 va = *reinterpret_cast<const short8*>(hin + (size_t)sa * C + seg);
#pragma unroll
                for (int q = 0; q < 8; ++q) acc[q] += bf2f((u16)va[q]);
            }
            if (jb < end) {
                int sb = csr[jb];
                short8 vb = *reinterpret_cast<const short8*>(hin + (size_t)sb * C + seg);
#pragma unroll
                for (int q = 0; q < 8; ++q) acc[q] += bf2f((u16)vb[q]);
            }
        }
#pragma unroll
        for (int q = 0; q < 8; ++q) {
            acc[q] += __shfl_xor(acc[q], 32);
            acc[q] += __shfl_xor(acc[q], 16);
        }
        if (lane < 16) {
            u16 o[8];
#pragma unroll
            for (int q = 0; q < 8; ++q) o[q] = f2bf(acc[q]);
            *reinterpret_cast<short8*>(&T[r * TSTRIDE + seg]) =
                *reinterpret_cast<const short8*>(o);
        }
    }

    // ---- stage B slice 0 ----
    {
        const short8* sp = reinterpret_cast<const short8*>(Bp);
        short8* dp = reinterpret_cast<short8*>(bsl[0]);
        dp[tid] = sp[tid];
        dp[tid + 256] = sp[tid + 256];
    }

    int arow = row0 + (lane & 15);
    int rclamp = arow < NN ? arow : NN - 1;
    int koff = (lane >> 4) * 8;

    // A-frags: agg part from LDS tile (own-wave rows), root part from global
    bf16x8 afr[8];
#pragma unroll
    for (int kk = 0; kk < 4; ++kk)
        afr[kk] = *reinterpret_cast<const bf16x8*>(&T[(lane & 15) * TSTRIDE + kk * 32 + koff]);
#pragma unroll
    for (int kk = 0; kk < 4; ++kk)
        afr[4 + kk] = *reinterpret_cast<const bf16x8*>(hin + (size_t)rclamp * C + kk * 32 + koff);

    f32x4 acc[8] = {};
#pragma unroll
    for (int kk = 0; kk < 8; ++kk) {
        __syncthreads();   // slice kk staged; prev slice fully consumed
        if (kk < 7) {
            const short8* sp = reinterpret_cast<const short8*>(Bp + (size_t)(kk + 1) * 4096);
            short8* dp = reinterpret_cast<short8*>(bsl[(kk + 1) & 1]);
            dp[tid] = sp[tid];
            dp[tid + 256] = sp[tid + 256];
        }
        const u16* bp = &bsl[kk & 1][lane * 8];
#pragma unroll
        for (int n = 0; n < 8; ++n) {
            bf16x8 b = *reinterpret_cast<const bf16x8*>(bp + n * 64 * 8);
            acc[n] = __builtin_amdgcn_mfma_f32_16x16x32_bf16(afr[kk], b, acc[n], 0, 0, 0);
        }
    }

    // ---- epilogue: bias/relu -> tile (overwrites agg rows; afr already in regs) ----
    int colbase = lane & 15;
    int rloc = (lane >> 4) * 4;
#pragma unroll
    for (int n = 0; n < 8; ++n) {
        int col = n * 16 + colbase;
        float bb = bias[col];
#pragma unroll
        for (int r = 0; r < 4; ++r) {
            float v = acc[n][r] + bb;
            if (RELU) v = fmaxf(v, 0.0f);
            T[(rloc + r) * TSTRIDE + col] = f2bf(v);
        }
    }
    __syncthreads();

#pragma unroll
    for (int k = 0; k < 4; ++k) {
        int idx = k * 64 + lane;
        int lr = idx >> 4;
        int off = (idx & 15) * 8;
        int ro = row0 + lr;
        if (ro < NN) {
            short8 v = *reinterpret_cast<const short8*>(&T[lr * TSTRIDE + off]);
            *reinterpret_cast<short8*>(hout + (size_t)ro * C + off) = v;
        }
    }

    if (TSUM) {
        if (tid < C) {
            int c = tid;
            int base = blockIdx.x * 64;
            float run = 0.0f;
            int curg = -1;
            for (int r = 0; r < 64; ++r) {
                int ro = base + r;
                if (ro >= NN) break;
                int g = batch[ro];
                if (g != curg) {
                    if (curg >= 0) atomicAdd(&Tpart[(size_t)curg * C + c], run);
                    run = 0.0f;
                    curg = g;
                }
                run += bf2f(tile[r >> 4][(r & 15) * TSTRIDE + c]);
            }
            if (curg >= 0) atomicAdd(&Tpart[(size_t)curg * C + c], run);
        }
    }
}

// ---------------------------------------------------------------------------
// k_gsum: layer-3 edge sum (separate from k_gout: the launch boundary gives
// cross-XCD ordering for free; in-kernel __threadfence was a 13x disaster).
// ---------------------------------------------------------------------------
__global__ __launch_bounds__(256) void k_gsum(
    const u16* __restrict__ h, const int* __restrict__ rp,
    const int* __restrict__ csr, const int* __restrict__ gstart,
    float* __restrict__ partial) {
    int b = blockIdx.x;
    int g = b >> 3;              // NSPLIT = 8
    int p = b & 7;
    int tid = threadIdx.x;
    int slot = tid >> 4;
    int seg = (tid & 15) * 8;

    int gs = gstart[g], ge = gstart[g + 1];
    int es = rp[gs], ee = rp[ge];
    int m = ee - es;
    int js = es + (int)(((long long)m * p) >> 3);
    int je = es + (int)(((long long)m * (p + 1)) >> 3);

    float acc[8] = {};
    int j = js + slot;
    for (; j + 48 < je; j += 64) {
        int r0 = csr[j];
        int r1 = csr[j + 16];
        int r2 = csr[j + 32];
        int r3 = csr[j + 48];
        short8 v0 = *reinterpret_cast<const short8*>(h + (size_t)r0 * C + seg);
        short8 v1 = *reinterpret_cast<const short8*>(h + (size_t)r1 * C + seg);
        short8 v2 = *reinterpret_cast<const short8*>(h + (size_t)r2 * C + seg);
        short8 v3 = *reinterpret_cast<const short8*>(h + (size_t)r3 * C + seg);
#pragma unroll
        for (int q = 0; q < 8; ++q) {
            acc[q] += bf2f((u16)v0[q]);
            acc[q] += bf2f((u16)v1[q]);
            acc[q] += bf2f((u16)v2[q]);
            acc[q] += bf2f((u16)v3[q]);
        }
    }
    for (; j < je; j += 16) {
        int r0 = csr[j];
        short8 v0 = *reinterpret_cast<const short8*>(h + (size_t)r0 * C + seg);
#pragma unroll
        for (int q = 0; q < 8; ++q) acc[q] += bf2f((u16)v0[q]);
    }

    __shared__ float red[16][C];
#pragma unroll
    for (int q = 0; q < 8; ++q) red[slot][seg + q] = acc[q];
    __syncthreads();
    if (tid < C) {
        float s = 0.0f;
#pragma unroll
        for (int r = 0; r < 16; ++r) s += red[r][tid];
        partial[(size_t)b * C + tid] = s;
    }
}

// ---------------------------------------------------------------------------
// k_gout: reduce NSPLIT S-partials + Tpart -> out_g = (S@Wrl + T@Wro)/n + bfold.
// ---------------------------------------------------------------------------
__global__ __launch_bounds__(128) void k_gout(
    const float* __restrict__ partial, const float* __restrict__ Tpart,
    const int* __restrict__ gstart,
    const float* __restrict__ Wrl, const float* __restrict__ Wro,
    const float* __restrict__ bfold, float* __restrict__ out) {
    int g = blockIdx.x;
    int k = threadIdx.x;
    __shared__ float S[C], T[C];
    float s = 0.0f;
#pragma unroll
    for (int p = 0; p < NSPLIT; ++p)
        s += partial[((size_t)(g * NSPLIT + p)) * C + k];
    S[k] = s;
    T[k] = Tpart[(size_t)g * C + k];
    __syncthreads();
    if (k < OC) {
        int n = gstart[g + 1] - gstart[g];
        float inv = 1.0f / (float)max(n, 1);
        float o = bfold[k];
#pragma unroll 8
        for (int kk = 0; kk < C; ++kk)
            o += (S[kk] * Wrl[kk * OC + k] + T[kk] * Wro[kk * OC + k]) * inv;
        out[g * OC + k] = o;
    }
}

extern "C" void kernel_launch(void* const* d_in, const int* in_sizes, int n_in,
                              void* d_out, int out_size, void* d_ws, size_t ws_size,
                              hipStream_t stream) {
    const float* x       = (const float*)d_in[0];
    const int*   eidx    = (const int*)d_in[1];
    const int*   batch   = (const int*)d_in[2];
    const float* W1_rel  = (const float*)d_in[3];
    const float* b1      = (const float*)d_in[4];
    const float* W1_root = (const float*)d_in[5];
    const float* W2_rel  = (const float*)d_in[6];
    const float* b2      = (const float*)d_in[7];
    const float* W2_root = (const float*)d_in[8];
    const float* W3_rel  = (const float*)d_in[9];
    const float* b3      = (const float*)d_in[10];
    const float* W3_root = (const float*)d_in[11];
    const float* W_lin   = (const float*)d_in[12];
    const float* b_lin   = (const float*)d_in[13];
    float* out = (float*)d_out;

    const int* src = eidx;
    const int* dst = eidx + NE;

    // Workspace layout (elements); gcnt+Tpart zeroed with one memset.
    u16* xb  = (u16*)d_ws;
    u16* hA  = xb + (size_t)NN * C;
    u16* hB  = hA + (size_t)NN * C;
    u16* Bp  = hB + (size_t)NN * C;
    int* rp      = (int*)(Bp + 2 * 32768);
    int* csr     = rp + NN + 1;
    int* buck    = csr + NE;
    int* gcnt    = buck + (size_t)BK * BCAP;
    float* Tpart = (float*)(gcnt + BK);
    int* gstart  = (int*)(Tpart + (size_t)NG * C);
    float* partial = (float*)(gstart + NG + 2);
    float* Wrl   = partial + (size_t)NG * NSPLIT * C;
    float* Wro   = Wrl + C * OC;
    float* bfold = Wro + C * OC;

    const int tb = (NN + 63) / 64;                // fused layer blocks (64 rows)

    // ---- zero gcnt + Tpart (one contiguous span) ----
    hipMemsetAsync(gcnt, 0, BK * sizeof(int) + (size_t)NG * C * sizeof(float),
                   stream);

    // ---- binA + all input-only precompute, merged & concurrent ----
    k_binA_prep<<<APB_TOT, 256, 0, stream>>>(src, dst, gcnt, buck,
                                             x, xb, W1_rel, W1_root, W2_rel, W2_root,
                                             Bp, batch, gstart,
                                             W3_rel, W3_root, b3, W_lin, b_lin,
                                             Wrl, Wro, bfold);

    // ---- bucket CSR build ----
    k_binB<<<BK, BNW, 0, stream>>>(gcnt, buck, rp, csr);

    // ---- Layer 1 (fused gather+transform): xb -> hA ----
    k_layer_fused<true, false><<<tb, 256, 0, stream>>>(xb, rp, csr, Bp, b1, hA,
                                                       batch, Tpart);

    // ---- Layer 2 (fused, + per-graph T sums): hA -> hB ----
    k_layer_fused<true, true><<<tb, 256, 0, stream>>>(hA, rp, csr, Bp + 32768, b2,
                                                      hB, batch, Tpart);

    // ---- Layer 3 edge-sum, then reduce + final GEMV ----
    k_gsum<<<NG * NSPLIT, 256, 0, stream>>>(hB, rp, csr, gstart, partial);
    k_gout<<<NG, 128, 0, stream>>>(partial, Tpart, gstart, Wrl, Wro, bfold, out);
}

// Round 19
// 294.988 us; speedup vs baseline: 1.1638x; 1.1638x over previous
//
#include <hip/hip_runtime.h>

static constexpr int NN = 100000;   // nodes
static constexpr int NE = 1600000;  // edges
static constexpr int C  = 128;      // feature dim
static constexpr int OC = 10;       // output classes
static constexpr int NG = 512;      // graphs

// Bucketed CSR build parameters
static constexpr int BSH  = 9;                         // 512 nodes per bucket
static constexpr int BNW  = 1 << BSH;                  // 512
static constexpr int BK   = (NN + BNW - 1) / BNW;      // 196 buckets
static constexpr int BCAP = 12288;                     // slab capacity (avg ~8163)
static constexpr int EPB  = 4096;                      // edges per binA block
static constexpr int ABLK = (NE + EPB - 1) / EPB;      // 391

static constexpr int TSTRIDE = 132;                    // LDS tile row stride (u16)
static constexpr int NSPLIT = 8;                       // blocks per graph in k_gsum

// merged binB+prep block-range bases (512-thread blocks)
static constexpr int PB_PACK = BK;                     // 16 blocks: weight pack
static constexpr int PB_GB   = PB_PACK + 16;           // 2 blocks: gbounds
static constexpr int PB_WF   = PB_GB + 2;              // 5 blocks: wfold
static constexpr int PB_CVT  = PB_WF + 5;              // 3125 blocks: x->bf16
static constexpr int PB_TOT  = PB_CVT + (NN * C / 8 + 511) / 512;

typedef unsigned short u16;
typedef __attribute__((ext_vector_type(8))) short short8;   // 8 bf16 = 16B
typedef __attribute__((ext_vector_type(8))) short bf16x8;   // MFMA A/B frag
typedef __attribute__((ext_vector_type(4))) float f32x4;    // MFMA C/D frag

__device__ __forceinline__ float bf2f(u16 u) {
    union { float f; unsigned int u32; } v; v.u32 = ((unsigned int)u) << 16; return v.f;
}
__device__ __forceinline__ u16 f2bf(float f) {
    union { float f; unsigned int u; } v; v.f = f;
    unsigned int u = v.u;
    unsigned int r = u + 0x7FFF + ((u >> 16) & 1);   // RNE
    return (u16)(r >> 16);
}

// ---------------------------------------------------------------------------
// Phase A: bin edges into BK buckets by dst>>BSH (L2-local slab writes).
// ---------------------------------------------------------------------------
__global__ __launch_bounds__(256) void k_binA(const int* __restrict__ src,
                                              const int* __restrict__ dst,
                                              int* __restrict__ gcnt,
                                              int* __restrict__ buck) {
    __shared__ int cnt[BK];
    __shared__ int curs[BK];
    int tid = threadIdx.x;
    for (int i = tid; i < BK; i += 256) cnt[i] = 0;
    __syncthreads();
    int e0 = blockIdx.x * EPB;
    for (int i = tid; i < EPB; i += 256) {
        int e = e0 + i;
        if (e < NE) atomicAdd(&cnt[dst[e] >> BSH], 1);
    }
    __syncthreads();
    for (int i = tid; i < BK; i += 256) {
        int c = cnt[i];
        int gb = (c > 0) ? atomicAdd(&gcnt[i], c) : 0;
        curs[i] = i * BCAP + gb;
    }
    __syncthreads();
    for (int i = tid; i < EPB; i += 256) {
        int e = e0 + i;
        if (e < NE) {
            int d = dst[e];
            int b = d >> BSH;
            int p = atomicAdd(&curs[b], 1);
            if (p < (b + 1) * BCAP)
                buck[p] = (src[e] << BSH) | (d & (BNW - 1));
        }
    }
}

// ---------------------------------------------------------------------------
// Merged binB + prep (512-thread heterogeneous blocks):
//   [0, BK)          : bucket CSR build (self-computed base via gcnt scan)
//   [PB_PACK, +16)   : pack L1/L2 [W_rel;W_root] -> MFMA B-frag order (bf16)
//   [PB_GB, +2)      : graph boundaries (binary search over sorted batch)
//   [PB_WF, +5)      : fold layer3+linear -> Wrl/Wro/bfold
//   [PB_CVT, ...)    : x f32 -> bf16
// ---------------------------------------------------------------------------
__global__ __launch_bounds__(512) void k_binbprep(
    const int* __restrict__ gcnt, const int* __restrict__ buck,
    int* __restrict__ rp, int* __restrict__ csr,
    const float* __restrict__ x, u16* __restrict__ xb,
    const float* __restrict__ W1r, const float* __restrict__ W1o,
    const float* __restrict__ W2r, const float* __restrict__ W2o,
    u16* __restrict__ Bp,
    const int* __restrict__ batch, int* __restrict__ gstart,
    const float* __restrict__ W3r, const float* __restrict__ W3o,
    const float* __restrict__ b3, const float* __restrict__ W_lin,
    const float* __restrict__ b_lin,
    float* __restrict__ Wrl, float* __restrict__ Wro, float* __restrict__ bfold) {
    int bid = blockIdx.x;
    int tid = threadIdx.x;

    if (bid < BK) {
        __shared__ int hist[BNW];
        __shared__ int scanbuf[BNW];
        int b = bid;

        scanbuf[tid] = (tid < b) ? gcnt[tid] : 0;
        __syncthreads();
        for (int off = 1; off < BNW; off <<= 1) {
            int t = (tid >= off) ? scanbuf[tid - off] : 0;
            __syncthreads();
            scanbuf[tid] += t;
            __syncthreads();
        }
        int base = scanbuf[BNW - 1];

        int n = gcnt[b];
        if (n > BCAP) n = BCAP;
        const int* bb = buck + (size_t)b * BCAP;

        hist[tid] = 0;
        __syncthreads();
        for (int i = tid; i < n; i += BNW) atomicAdd(&hist[bb[i] & (BNW - 1)], 1);
        __syncthreads();

        int v = hist[tid];
        scanbuf[tid] = v;
        __syncthreads();
        for (int off = 1; off < BNW; off <<= 1) {
            int t = (tid >= off) ? scanbuf[tid - off] : 0;
            __syncthreads();
            scanbuf[tid] += t;
            __syncthreads();
        }
        int excl = scanbuf[tid] - v;
        int node = (b << BSH) + tid;
        if (node < NN) rp[node] = base + excl;
        if (b == 0 && tid == 0) rp[NN] = NE;
        __syncthreads();
        hist[tid] = base + excl;      // cursor
        __syncthreads();
        for (int i = tid; i < n; i += BNW) {
            int en = bb[i];
            int p = atomicAdd(&hist[en & (BNW - 1)], 1);
            csr[p] = en >> BSH;
        }
    } else if (bid < PB_GB) {
        int tt = (bid - PB_PACK) * 512 + tid;     // 0..8191
        int layer = tt >> 12;
        int t = tt & 4095;
        const float* Wr = (layer == 0) ? W1r : W2r;
        const float* Wo = (layer == 0) ? W1o : W2o;
        u16* outp = Bp + layer * 32768;
        int lane = t & 63;
        int nfrag = (t >> 6) & 7;
        int kk = t >> 9;
        int col = nfrag * 16 + (lane & 15);
        int k0 = kk * 32 + (lane >> 4) * 8;
        u16 vals[8];
#pragma unroll
        for (int j = 0; j < 8; ++j) {
            int k = k0 + j;
            float w = (k < C) ? Wr[k * C + col] : Wo[(k - C) * C + col];
            vals[j] = f2bf(w);
        }
        *reinterpret_cast<short8*>(outp + (size_t)t * 8) = *reinterpret_cast<const short8*>(vals);
    } else if (bid < PB_WF) {
        int g = (bid - PB_GB) * 512 + tid;
        if (g > NG) return;
        int lo = 0, hi = NN;
        while (lo < hi) { int mid = (lo + hi) >> 1; if (batch[mid] < g) lo = mid + 1; else hi = mid; }
        gstart[g] = lo;
    } else if (bid < PB_CVT) {
        int idx = (bid - PB_WF) * 512 + tid;
        if (idx >= OC * 256) return;
        int o = idx >> 8;
        int sub = idx & 255;
        if (sub < 128) {
            float s = 0.0f;
#pragma unroll 8
            for (int c = 0; c < C; ++c) s += W3r[sub * C + c] * W_lin[c * OC + o];
            Wrl[sub * OC + o] = s;
        } else {
            int k = sub - 128;
            float s = 0.0f;
#pragma unroll 8
            for (int c = 0; c < C; ++c) s += W3o[k * C + c] * W_lin[c * OC + o];
            Wro[k * OC + o] = s;
        }
        if (sub == 0) {
            float s = 0.0f;
            for (int c = 0; c < C; ++c) s += b3[c] * W_lin[c * OC + o];
            bfold[o] = b_lin[o] + s;
        }
    } else {
        int i = (bid - PB_CVT) * 512 + tid;
        size_t base = (size_t)i * 8;
        if (base >= (size_t)NN * C) return;
        float4 a = *reinterpret_cast<const float4*>(x + base);
        float4 b = *reinterpret_cast<const float4*>(x + base + 4);
        u16 o[8] = { f2bf(a.x), f2bf(a.y), f2bf(a.z), f2bf(a.w),
                     f2bf(b.x), f2bf(b.y), f2bf(b.z), f2bf(b.w) };
        *reinterpret_cast<short8*>(xb + base) = *reinterpret_cast<const short8*>(o);
    }
}

// ---------------------------------------------------------------------------
// Gather-aggregate (bf16): agg[i] = sum_{j in in(i)} h[j].
// Whole wave per node: lane = (jj 0..3, seg 0..15); 8 edges/iteration.
// Pinned at the random-row service ceiling (58 us across 5 implementations).
// ---------------------------------------------------------------------------
__global__ __launch_bounds__(256) void k_gather(const u16* __restrict__ h,
                                                const int* __restrict__ rp,
                                                const int* __restrict__ csr,
                                                u16* __restrict__ agg) {
    int t = blockIdx.x * blockDim.x + threadIdx.x;
    int node = t >> 6;
    if (node >= NN) return;
    int lane = t & 63;
    int jj = lane >> 4;          // edge slot 0..3
    int seg = (lane & 15) * 8;   // element offset within row
    int beg = rp[node], end = rp[node + 1];

    float acc[8] = {};
    int j0 = beg;
    for (; j0 + 8 <= end; j0 += 8) {
        int sa = csr[j0 + jj];
        int sb = csr[j0 + 4 + jj];
        short8 va = *reinterpret_cast<const short8*>(h + (size_t)sa * C + seg);
        short8 vb = *reinterpret_cast<const short8*>(h + (size_t)sb * C + seg);
#pragma unroll
        for (int q = 0; q < 8; ++q) {
            acc[q] += bf2f((u16)va[q]);
            acc[q] += bf2f((u16)vb[q]);
        }
    }
    if (j0 < end) {
        int ja = j0 + jj;
        int jb = j0 + 4 + jj;
        if (ja < end) {
            int sa = csr[ja];
            short8 va = *reinterpret_cast<const short8*>(h + (size_t)sa * C + seg);
#pragma unroll
            for (int q = 0; q < 8; ++q) acc[q] += bf2f((u16)va[q]);
        }
        if (jb < end) {
            int sb = csr[jb];
            short8 vb = *reinterpret_cast<const short8*>(h + (size_t)sb * C + seg);
#pragma unroll
            for (int q = 0; q < 8; ++q) acc[q] += bf2f((u16)vb[q]);
        }
    }

#pragma unroll
    for (int q = 0; q < 8; ++q) {
        acc[q] += __shfl_xor(acc[q], 32);
        acc[q] += __shfl_xor(acc[q], 16);
    }
    if (lane < 16) {
        u16 o[8];
#pragma unroll
        for (int q = 0; q < 8; ++q) o[q] = f2bf(acc[q]);
        *reinterpret_cast<short8*>(agg + (size_t)node * C + seg) =
            *reinterpret_cast<const short8*>(o);
    }
}

// ---------------------------------------------------------------------------
// MFMA transform: out = [relu]( [agg|h] @ [W_rel;W_root] + b ), bf16 in/out.
// All 8 A-fragments prefetched into registers before the MFMA loop.
// LDS-staged coalesced epilogue.  Safe in-place.
// TSUM: accumulate per-graph column sums of the output tile into Tpart.
// ---------------------------------------------------------------------------
template <bool RELU, bool TSUM>
__global__ __launch_bounds__(256) void k_transform_mfma(
    const u16* __restrict__ agg, const u16* __restrict__ h,
    const u16* __restrict__ Bp, const float* __restrict__ bias,
    u16* __restrict__ out,
    const int* __restrict__ batch, float* __restrict__ Tpart) {
    __shared__ u16 tile[4][16 * TSTRIDE];   // 16.9 KB
    int tid = threadIdx.x;
    int wave = tid >> 6;
    int lane = tid & 63;
    int row0 = blockIdx.x * 64 + wave * 16;
    int arow = row0 + (lane & 15);
    int rclamp = arow < NN ? arow : NN - 1;
    int koff = (lane >> 4) * 8;

    // prefetch all 8 A-fragments (4 from agg, 4 from h)
    bf16x8 afr[8];
#pragma unroll
    for (int kk = 0; kk < 4; ++kk)
        afr[kk] = *reinterpret_cast<const bf16x8*>(agg + (size_t)rclamp * C + kk * 32 + koff);
#pragma unroll
    for (int kk = 0; kk < 4; ++kk)
        afr[4 + kk] = *reinterpret_cast<const bf16x8*>(h + (size_t)rclamp * C + kk * 32 + koff);

    f32x4 acc[8] = {};
#pragma unroll
    for (int kk = 0; kk < 8; ++kk) {
        const u16* bp = Bp + ((size_t)kk * 8 * 64 + lane) * 8;
#pragma unroll
        for (int n = 0; n < 8; ++n) {
            bf16x8 b = *reinterpret_cast<const bf16x8*>(bp + (size_t)n * 64 * 8);
            acc[n] = __builtin_amdgcn_mfma_f32_16x16x32_bf16(afr[kk], b, acc[n], 0, 0, 0);
        }
    }

    u16* T = tile[wave];
    int colbase = lane & 15;
    int rloc = (lane >> 4) * 4;
#pragma unroll
    for (int n = 0; n < 8; ++n) {
        int col = n * 16 + colbase;
        float bb = bias[col];
#pragma unroll
        for (int r = 0; r < 4; ++r) {
            float v = acc[n][r] + bb;
            if (RELU) v = fmaxf(v, 0.0f);
            T[(rloc + r) * TSTRIDE + col] = f2bf(v);
        }
    }
    __syncthreads();

#pragma unroll
    for (int k = 0; k < 4; ++k) {
        int idx = k * 64 + lane;
        int lr = idx >> 4;
        int off = (idx & 15) * 8;
        int ro = row0 + lr;
        if (ro < NN) {
            short8 v = *reinterpret_cast<const short8*>(&T[lr * TSTRIDE + off]);
            *reinterpret_cast<short8*>(out + (size_t)ro * C + off) = v;
        }
    }

    if (TSUM) {
        if (tid < C) {
            int c = tid;
            int base = blockIdx.x * 64;
            float run = 0.0f;
            int curg = -1;
            for (int r = 0; r < 64; ++r) {
                int ro = base + r;
                if (ro >= NN) break;
                int g = batch[ro];
                if (g != curg) {
                    if (curg >= 0) atomicAdd(&Tpart[(size_t)curg * C + c], run);
                    run = 0.0f;
                    curg = g;
                }
                run += bf2f(tile[r >> 4][(r & 15) * TSTRIDE + c]);
            }
            if (curg >= 0) atomicAdd(&Tpart[(size_t)curg * C + c], run);
        }
    }
}

// ---------------------------------------------------------------------------
// k_gsum: layer-3 edge sum.  Per graph g (NSPLIT blocks each):
// S_g = sum over its contiguous CSR edge window of h2[src].  ILP-4 loop.
// ---------------------------------------------------------------------------
__global__ __launch_bounds__(256) void k_gsum(
    const u16* __restrict__ h, const int* __restrict__ rp,
    const int* __restrict__ csr, const int* __restrict__ gstart,
    float* __restrict__ partial) {
    int b = blockIdx.x;
    int g = b >> 3;              // NSPLIT = 8
    int p = b & 7;
    int slot = threadIdx.x >> 4; // 0..15
    int seg = (threadIdx.x & 15) * 8;

    int gs = gstart[g], ge = gstart[g + 1];
    int es = rp[gs], ee = rp[ge];
    int m = ee - es;
    int js = es + (int)(((long long)m * p) >> 3);
    int je = es + (int)(((long long)m * (p + 1)) >> 3);

    float acc[8] = {};
    int j = js + slot;
    for (; j + 48 < je; j += 64) {
        int r0 = csr[j];
        int r1 = csr[j + 16];
        int r2 = csr[j + 32];
        int r3 = csr[j + 48];
        short8 v0 = *reinterpret_cast<const short8*>(h + (size_t)r0 * C + seg);
        short8 v1 = *reinterpret_cast<const short8*>(h + (size_t)r1 * C + seg);
        short8 v2 = *reinterpret_cast<const short8*>(h + (size_t)r2 * C + seg);
        short8 v3 = *reinterpret_cast<const short8*>(h + (size_t)r3 * C + seg);
#pragma unroll
        for (int q = 0; q < 8; ++q) {
            acc[q] += bf2f((u16)v0[q]);
            acc[q] += bf2f((u16)v1[q]);
            acc[q] += bf2f((u16)v2[q]);
            acc[q] += bf2f((u16)v3[q]);
        }
    }
    for (; j < je; j += 16) {
        int r0 = csr[j];
        short8 v0 = *reinterpret_cast<const short8*>(h + (size_t)r0 * C + seg);
#pragma unroll
        for (int q = 0; q < 8; ++q) acc[q] += bf2f((u16)v0[q]);
    }

    __shared__ float red[16][C];   // 8 KB
#pragma unroll
    for (int q = 0; q < 8; ++q) red[slot][seg + q] = acc[q];
    __syncthreads();
    if (threadIdx.x < C) {
        float s = 0.0f;
#pragma unroll
        for (int r = 0; r < 16; ++r) s += red[r][threadIdx.x];
        partial[(size_t)b * C + threadIdx.x] = s;
    }
}

// ---------------------------------------------------------------------------
// k_gout: reduce NSPLIT S-partials + read Tpart, then
// out_g = (S@Wrl + T@Wro)/n + bfold.  Grid = NG blocks x 128 threads.
// ---------------------------------------------------------------------------
__global__ __launch_bounds__(128) void k_gout(
    const float* __restrict__ partial, const float* __restrict__ Tpart,
    const int* __restrict__ gstart,
    const float* __restrict__ Wrl, const float* __restrict__ Wro,
    const float* __restrict__ bfold, float* __restrict__ out) {
    int g = blockIdx.x;
    int k = threadIdx.x;
    __shared__ float S[C], T[C];
    float s = 0.0f;
#pragma unroll
    for (int p = 0; p < NSPLIT; ++p)
        s += partial[((size_t)(g * NSPLIT + p)) * C + k];
    S[k] = s;
    T[k] = Tpart[(size_t)g * C + k];
    __syncthreads();
    if (k < OC) {
        int n = gstart[g + 1] - gstart[g];
        float inv = 1.0f / (float)max(n, 1);
        float o = bfold[k];
#pragma unroll 8
        for (int kk = 0; kk < C; ++kk)
            o += (S[kk] * Wrl[kk * OC + k] + T[kk] * Wro[kk * OC + k]) * inv;
        out[g * OC + k] = o;
    }
}

extern "C" void kernel_launch(void* const* d_in, const int* in_sizes, int n_in,
                              void* d_out, int out_size, void* d_ws, size_t ws_size,
                              hipStream_t stream) {
    const float* x       = (const float*)d_in[0];
    const int*   eidx    = (const int*)d_in[1];
    const int*   batch   = (const int*)d_in[2];
    const float* W1_rel  = (const float*)d_in[3];
    const float* b1      = (const float*)d_in[4];
    const float* W1_root = (const float*)d_in[5];
    const float* W2_rel  = (const float*)d_in[6];
    const float* b2      = (const float*)d_in[7];
    const float* W2_root = (const float*)d_in[8];
    const float* W3_rel  = (const float*)d_in[9];
    const float* b3      = (const float*)d_in[10];
    const float* W3_root = (const float*)d_in[11];
    const float* W_lin   = (const float*)d_in[12];
    const float* b_lin   = (const float*)d_in[13];
    float* out = (float*)d_out;

    const int* src = eidx;
    const int* dst = eidx + NE;

    // Workspace layout (elements); gcnt+Tpart zeroed with one memset.
    u16* xb   = (u16*)d_ws;
    u16* hb   = xb + (size_t)NN * C;
    u16* aggb = hb + (size_t)NN * C;
    u16* Bp   = aggb + (size_t)NN * C;
    int* rp      = (int*)(Bp + 2 * 32768);
    int* csr     = rp + NN + 1;
    int* buck    = csr + NE;
    int* gcnt    = buck + (size_t)BK * BCAP;
    float* Tpart = (float*)(gcnt + BK);
    int* gstart  = (int*)(Tpart + (size_t)NG * C);
    float* partial = (float*)(gstart + NG + 2);
    float* Wrl   = partial + (size_t)NG * NSPLIT * C;
    float* Wro   = Wrl + C * OC;
    float* bfold = Wro + C * OC;

    const int gb = (NN * 64 + 255) / 256;         // gather blocks (64 lanes/node)
    const int tb = (NN + 63) / 64;                // transform blocks (64 rows)

    // ---- zero gcnt + Tpart (one contiguous span) ----
    hipMemsetAsync(gcnt, 0, BK * sizeof(int) + (size_t)NG * C * sizeof(float), stream);

    // ---- bucketed CSR build phase A ----
    k_binA<<<ABLK, 256, 0, stream>>>(src, dst, gcnt, buck);

    // ---- binB + all precompute, merged & concurrent ----
    k_binbprep<<<PB_TOT, 512, 0, stream>>>(gcnt, buck, rp, csr,
                                           x, xb, W1_rel, W1_root, W2_rel, W2_root,
                                           Bp, batch, gstart,
                                           W3_rel, W3_root, b3, W_lin, b_lin,
                                           Wrl, Wro, bfold);

    // ---- Layer 1 ----
    k_gather<<<gb, 256, 0, stream>>>(xb, rp, csr, aggb);
    k_transform_mfma<true, false><<<tb, 256, 0, stream>>>(aggb, xb, Bp, b1, hb,
                                                          batch, Tpart);

    // ---- Layer 2 (in-place; epilogue accumulates per-graph T sums) ----
    k_gather<<<gb, 256, 0, stream>>>(hb, rp, csr, aggb);
    k_transform_mfma<true, true><<<tb, 256, 0, stream>>>(aggb, hb, Bp + 32768, b2,
                                                         hb, batch, Tpart);

    // ---- Layer 3 + mean-pool + final linear, algebraically collapsed ----
    k_gsum<<<NG * NSPLIT, 256, 0, stream>>>(hb, rp, csr, gstart, partial);
    k_gout<<<NG, 128, 0, stream>>>(partial, Tpart, gstart, Wrl, Wro, bfold, out);
}